// Round 4
// baseline (279.105 us; speedup 1.0000x reference)
//
#include <hip/hip_runtime.h>
#include <cstdint>
#include <cstddef>

#define NROWS 4096
#define DIM   1024
#define TWON  8192
#define INV_T 2.0f
// exp(2.0) = exp(sim_rr / T) for the masked diagonal (rows are unit-norm)
#define EXP_DIAG 7.38905609893065f
#define NTILES (64 * 65 / 2)

typedef __bf16 bf16x8 __attribute__((ext_vector_type(8)));
typedef float  floatx4 __attribute__((ext_vector_type(4)));

__device__ __forceinline__ unsigned short f2bf(float f) {
  union { float f; unsigned int u; } a; a.f = f;
  a.u += 0x7FFFu + ((a.u >> 16) & 1u);   // RNE
  return (unsigned short)(a.u >> 16);
}

__device__ __forceinline__ void gload16(const unsigned short* g, unsigned short* l) {
  __builtin_amdgcn_global_load_lds(
      (const __attribute__((address_space(1))) void*)g,
      (__attribute__((address_space(3))) void*)l,
      16, 0, 0);
}

// -- kernel 1: normalize rows k and k+N, fp32 positive dot -> pos[], zero denom
__global__ __launch_bounds__(256) void normpos_kernel(
    const float* __restrict__ emb_i, const float* __restrict__ emb_j,
    unsigned short* __restrict__ reps, float* __restrict__ denom,
    float* __restrict__ pos, unsigned int* __restrict__ cnt) {
  const int k = blockIdx.x;                   // 0..4095 (pair index)
  const int t = threadIdx.x;                  // 256 threads, 4 floats per row
  if (k < 32) denom[k * 256 + t] = 0.f;       // stream-ordered before simsum
  if (k == 32 && t == 0) *cnt = 0u;           // completion counter for simsum

  float4 vi = reinterpret_cast<const float4*>(emb_i + (size_t)k * DIM)[t];
  float4 vj = reinterpret_cast<const float4*>(emb_j + (size_t)k * DIM)[t];
  float ssi = vi.x * vi.x + vi.y * vi.y + vi.z * vi.z + vi.w * vi.w;
  float ssj = vj.x * vj.x + vj.y * vj.y + vj.z * vj.z + vj.w * vj.w;
  float dot = vi.x * vj.x + vi.y * vj.y + vi.z * vj.z + vi.w * vj.w;
#pragma unroll
  for (int o = 32; o; o >>= 1) {
    ssi += __shfl_down(ssi, o, 64);
    ssj += __shfl_down(ssj, o, 64);
    dot += __shfl_down(dot, o, 64);
  }
  __shared__ float red[3][4];
  if ((t & 63) == 0) {
    red[0][t >> 6] = ssi; red[1][t >> 6] = ssj; red[2][t >> 6] = dot;
  }
  __syncthreads();
  float ti = red[0][0] + red[0][1] + red[0][2] + red[0][3];
  float tj = red[1][0] + red[1][1] + red[1][2] + red[1][3];
  float invi = 1.0f / fmaxf(sqrtf(ti), 1e-12f);
  float invj = 1.0f / fmaxf(sqrtf(tj), 1e-12f);
  ushort4 oi, oj;
  oi.x = f2bf(vi.x * invi); oi.y = f2bf(vi.y * invi);
  oi.z = f2bf(vi.z * invi); oi.w = f2bf(vi.w * invi);
  oj.x = f2bf(vj.x * invj); oj.y = f2bf(vj.y * invj);
  oj.z = f2bf(vj.z * invj); oj.w = f2bf(vj.w * invj);
  reinterpret_cast<ushort4*>(reps + (size_t)k * DIM)[t] = oi;
  reinterpret_cast<ushort4*>(reps + (size_t)(k + NROWS) * DIM)[t] = oj;
  if (t == 0) {
    float td = red[2][0] + red[2][1] + red[2][2] + red[2][3];
    pos[k] = td * invi * invj;   // cosine of the positive pair, fp32
  }
}

// ------- kernel 2: fused sim-GEMM + exp + row/col sums, upper triangle -------
// C-tile 128x128, 4 waves 2x2, each wave 4x4 grid of 16x16x32 MFMAs, BK=32.
// LDS staging is XOR-swizzled by row&3 (16B chunks) so fragment ds_read_b128s
// spread over all 32 banks (global_load_lds forbids padding; swizzle the
// SOURCE address instead — lane->LDS-slot mapping stays identity).
// Last block to finish also computes the final loss (completion counter).
__global__ __launch_bounds__(256) void simsum_kernel(
    const unsigned short* __restrict__ reps, float* __restrict__ denom,
    const float* __restrict__ pos, unsigned int* __restrict__ cnt,
    float* __restrict__ out) {
  __shared__ __align__(16) unsigned short lA[128 * 32];  // 8 KB
  __shared__ __align__(16) unsigned short lB[128 * 32];  // 8 KB
  __shared__ float dl[128];   // row-side partial sums
  __shared__ float cl[128];   // col-side partial sums

  const int t    = threadIdx.x;
  const int lane = t & 63;
  const int wave = t >> 6;
  const int wm   = wave >> 1;      // wave row 0..1
  const int wn   = wave & 1;       // wave col 0..1

  // triangular unranking: f(b) = b*(129-b)/2 tiles before block-row b
  const int idx = blockIdx.x;      // 0..2079
  int brow = (int)(64.5f - sqrtf(64.5f * 64.5f - 2.0f * (float)idx));
  if (brow > 63) brow = 63;
  if (brow < 0) brow = 0;
  while ((brow + 1) * (129 - (brow + 1)) / 2 <= idx) ++brow;
  while (brow * (129 - brow) / 2 > idx) --brow;
  const int bcol = brow + (idx - brow * (129 - brow) / 2);
  const bool offdiag = (brow != bcol);

  const unsigned short* gA = reps + (size_t)brow * 128 * DIM;
  const unsigned short* gB = reps + (size_t)bcol * 128 * DIM;

  // staging: thread t serves row srow, swizzled 16B chunk within the k-window
  const int srow  = t >> 2;                        // 0..63
  const int scswz = (((t & 3) ^ (srow & 3)) << 3); // swizzled short offset
  const size_t gOff = (size_t)srow * DIM + scswz;

  floatx4 acc[4][4];
#pragma unroll
  for (int i = 0; i < 4; ++i)
#pragma unroll
    for (int j = 0; j < 4; ++j) acc[i][j] = floatx4{0.f, 0.f, 0.f, 0.f};

  const int mrow = lane & 15;        // fragment row select
  const int hi   = lane >> 4;        // k quad 0..3
  const int cswz = ((hi ^ (mrow & 3)) << 3);  // swizzled chunk (wm*64,mt*16 ≡0 mod 4)

  for (int k0 = 0; k0 < DIM; k0 += 32) {
    __syncthreads();
    gload16(gA + gOff + k0, lA + t * 8);
    gload16(gA + gOff + (size_t)64 * DIM + k0, lA + 2048 + t * 8);
    gload16(gB + gOff + k0, lB + t * 8);
    gload16(gB + gOff + (size_t)64 * DIM + k0, lB + 2048 + t * 8);
    __syncthreads();   // compiler inserts vmcnt(0) drain here

    bf16x8 af[4], bq[4];
#pragma unroll
    for (int mt = 0; mt < 4; ++mt)
      af[mt] = *reinterpret_cast<const bf16x8*>(&lA[(wm * 64 + mt * 16 + mrow) * 32 + cswz]);
#pragma unroll
    for (int nt = 0; nt < 4; ++nt)
      bq[nt] = *reinterpret_cast<const bf16x8*>(&lB[(wn * 64 + nt * 16 + mrow) * 32 + cswz]);
#pragma unroll
    for (int mt = 0; mt < 4; ++mt)
#pragma unroll
      for (int nt = 0; nt < 4; ++nt)
        acc[mt][nt] = __builtin_amdgcn_mfma_f32_16x16x32_bf16(af[mt], bq[nt], acc[mt][nt], 0, 0, 0);
  }

  if (t < 128) dl[t] = 0.f; else cl[t - 128] = 0.f;
  __syncthreads();

  // exp in-place: acc now holds e = exp(sim/T)
#pragma unroll
  for (int mt = 0; mt < 4; ++mt)
#pragma unroll
    for (int nt = 0; nt < 4; ++nt)
#pragma unroll
      for (int r = 0; r < 4; ++r)
        acc[mt][nt][r] = __expf(acc[mt][nt][r] * INV_T);

  // row-sums: C/D layout (16x16): col = lane&15, row = (lane>>4)*4 + reg [m89]
#pragma unroll
  for (int mt = 0; mt < 4; ++mt) {
#pragma unroll
    for (int r = 0; r < 4; ++r) {
      float s = acc[mt][0][r] + acc[mt][1][r] + acc[mt][2][r] + acc[mt][3][r];
      s += __shfl_xor(s, 1, 64);
      s += __shfl_xor(s, 2, 64);
      s += __shfl_xor(s, 4, 64);
      s += __shfl_xor(s, 8, 64);
      if ((lane & 15) == 0)
        atomicAdd(&dl[wm * 64 + mt * 16 + (lane >> 4) * 4 + r], s);
    }
  }

  // col-sums (mirror rows), off-diag tiles only
  if (offdiag) {
#pragma unroll
    for (int nt = 0; nt < 4; ++nt) {
      float c = 0.f;
#pragma unroll
      for (int mt = 0; mt < 4; ++mt)
#pragma unroll
        for (int r = 0; r < 4; ++r) c += acc[mt][nt][r];
      c += __shfl_xor(c, 16, 64);
      c += __shfl_xor(c, 32, 64);
      if ((lane >> 4) == 0)
        atomicAdd(&cl[wn * 64 + nt * 16 + (lane & 15)], c);
    }
  }
  __syncthreads();
  if (t < 128) {
    atomicAdd(&denom[brow * 128 + t], dl[t]);
    if (offdiag) atomicAdd(&denom[bcol * 128 + t], cl[t]);
  }

  // ---- last-block-done epilogue: final loss reduction, no extra dispatch ----
  __threadfence();
  __shared__ unsigned int is_last;
  if (t == 0)
    is_last = (atomicAdd(cnt, 1u) == NTILES - 1) ? 1u : 0u;
  __syncthreads();
  if (is_last) {
    float v = 0.f;
#pragma unroll
    for (int i = 0; i < TWON / 256; ++i) {
      float d = __hip_atomic_load(&denom[i * 256 + t], __ATOMIC_RELAXED,
                                  __HIP_MEMORY_SCOPE_AGENT);
      v += __logf(d - EXP_DIAG);
    }
    float p = 0.f;
#pragma unroll
    for (int i = 0; i < NROWS / 256; ++i)
      p += pos[i * 256 + t];
    v -= 4.0f * p;
#pragma unroll
    for (int o = 32; o; o >>= 1) v += __shfl_down(v, o, 64);
    if ((t & 63) == 0) dl[t >> 6] = v;
    __syncthreads();
    if (t == 0)
      out[0] = (dl[0] + dl[1] + dl[2] + dl[3]) * (1.0f / 8192.0f);
  }
}

extern "C" void kernel_launch(void* const* d_in, const int* in_sizes, int n_in,
                              void* d_out, int out_size, void* d_ws, size_t ws_size,
                              hipStream_t stream) {
  const float* emb_i = (const float*)d_in[0];
  const float* emb_j = (const float*)d_in[1];
  float* out = (float*)d_out;

  unsigned short* reps = (unsigned short*)d_ws;                    // 16.78 MB bf16
  float* denom = (float*)((char*)d_ws + (size_t)TWON * DIM * 2);   // 32 KB
  float* pos   = denom + TWON;                                     // 16 KB
  unsigned int* cnt = (unsigned int*)(pos + NROWS);

  normpos_kernel<<<NROWS, 256, 0, stream>>>(emb_i, emb_j, reps, denom, pos, cnt);
  simsum_kernel<<<NTILES, 256, 0, stream>>>(reps, denom, pos, cnt, out);
}

// Round 5
// 181.994 us; speedup vs baseline: 1.5336x; 1.5336x over previous
//
#include <hip/hip_runtime.h>
#include <cstdint>
#include <cstddef>

#define NROWS 4096
#define DIM   1024
#define TWON  8192
#define INV_T 2.0f
// exp(2.0) = exp(sim_rr / T) for the masked diagonal (rows are unit-norm)
#define EXP_DIAG 7.38905609893065f
#define NTILES (64 * 65 / 2)

typedef __bf16 bf16x8 __attribute__((ext_vector_type(8)));
typedef float  floatx4 __attribute__((ext_vector_type(4)));

__device__ __forceinline__ unsigned short f2bf(float f) {
  union { float f; unsigned int u; } a; a.f = f;
  a.u += 0x7FFFu + ((a.u >> 16) & 1u);   // RNE
  return (unsigned short)(a.u >> 16);
}

__device__ __forceinline__ void gload16(const unsigned short* g, unsigned short* l) {
  __builtin_amdgcn_global_load_lds(
      (const __attribute__((address_space(1))) void*)g,
      (__attribute__((address_space(3))) void*)l,
      16, 0, 0);
}

// -- kernel 1: normalize rows k and k+N, fp32 positive dot -> pos[], zero denom
__global__ __launch_bounds__(256) void normpos_kernel(
    const float* __restrict__ emb_i, const float* __restrict__ emb_j,
    unsigned short* __restrict__ reps, float* __restrict__ denom,
    float* __restrict__ pos, unsigned int* __restrict__ cnt) {
  const int k = blockIdx.x;                   // 0..4095 (pair index)
  const int t = threadIdx.x;                  // 256 threads, 4 floats per row
  if (k < 32) denom[k * 256 + t] = 0.f;       // stream-ordered before simsum
  if (k == 32 && t == 0) *cnt = 0u;           // completion counter for simsum

  float4 vi = reinterpret_cast<const float4*>(emb_i + (size_t)k * DIM)[t];
  float4 vj = reinterpret_cast<const float4*>(emb_j + (size_t)k * DIM)[t];
  float ssi = vi.x * vi.x + vi.y * vi.y + vi.z * vi.z + vi.w * vi.w;
  float ssj = vj.x * vj.x + vj.y * vj.y + vj.z * vj.z + vj.w * vj.w;
  float dot = vi.x * vj.x + vi.y * vj.y + vi.z * vj.z + vi.w * vj.w;
#pragma unroll
  for (int o = 32; o; o >>= 1) {
    ssi += __shfl_down(ssi, o, 64);
    ssj += __shfl_down(ssj, o, 64);
    dot += __shfl_down(dot, o, 64);
  }
  __shared__ float red[3][4];
  if ((t & 63) == 0) {
    red[0][t >> 6] = ssi; red[1][t >> 6] = ssj; red[2][t >> 6] = dot;
  }
  __syncthreads();
  float ti = red[0][0] + red[0][1] + red[0][2] + red[0][3];
  float tj = red[1][0] + red[1][1] + red[1][2] + red[1][3];
  float invi = 1.0f / fmaxf(sqrtf(ti), 1e-12f);
  float invj = 1.0f / fmaxf(sqrtf(tj), 1e-12f);
  ushort4 oi, oj;
  oi.x = f2bf(vi.x * invi); oi.y = f2bf(vi.y * invi);
  oi.z = f2bf(vi.z * invi); oi.w = f2bf(vi.w * invi);
  oj.x = f2bf(vj.x * invj); oj.y = f2bf(vj.y * invj);
  oj.z = f2bf(vj.z * invj); oj.w = f2bf(vj.w * invj);
  reinterpret_cast<ushort4*>(reps + (size_t)k * DIM)[t] = oi;
  reinterpret_cast<ushort4*>(reps + (size_t)(k + NROWS) * DIM)[t] = oj;
  if (t == 0) {
    float td = red[2][0] + red[2][1] + red[2][2] + red[2][3];
    pos[k] = td * invi * invj;   // cosine of the positive pair, fp32
  }
}

// ------- kernel 2: fused sim-GEMM + exp + row/col sums, upper triangle -------
// C-tile 128x128, 4 waves 2x2, each wave 4x4 grid of 16x16x32 MFMAs, BK=32.
// LDS: ONE interleaved tile lAB[128 rows][64 shorts] (A chunk 0-3 | B chunk
// 0-3 per row, logical chunks XOR-swizzled by row&7). Row stride = 128 B so
// bank index is row-independent; 8-slot swizzle gives 2 lanes/bank (free).
// This replicates round-3's measured-zero-conflict layout at 16 KB LDS.
// Last block to finish computes the final loss (completion counter, NO
// threadfence — round 4 showed per-block buffer_wbl2 halves the kernel).
__global__ __launch_bounds__(256) void simsum_kernel(
    const unsigned short* __restrict__ reps, float* __restrict__ denom,
    const float* __restrict__ pos, unsigned int* __restrict__ cnt,
    float* __restrict__ out) {
  __shared__ __align__(16) unsigned short lAB[128 * 64];  // 16 KB
  __shared__ float dl[128];   // row-side partial sums
  __shared__ float cl[128];   // col-side partial sums
  __shared__ unsigned int is_last;

  const int t    = threadIdx.x;
  const int lane = t & 63;
  const int wave = t >> 6;
  const int wm   = wave >> 1;      // wave row 0..1
  const int wn   = wave & 1;       // wave col 0..1

  // triangular unranking: f(b) = b*(129-b)/2 tiles before block-row b
  const int idx = blockIdx.x;      // 0..2079
  int brow = (int)(64.5f - sqrtf(64.5f * 64.5f - 2.0f * (float)idx));
  if (brow > 63) brow = 63;
  if (brow < 0) brow = 0;
  while ((brow + 1) * (129 - (brow + 1)) / 2 <= idx) ++brow;
  while (brow * (129 - brow) / 2 > idx) --brow;
  const int bcol = brow + (idx - brow * (129 - brow) / 2);
  const bool offdiag = (brow != bcol);

  const unsigned short* gA = reps + (size_t)brow * 128 * DIM;
  const unsigned short* gB = reps + (size_t)bcol * 128 * DIM;

  // staging: slotIdx = q*256 + t; row r = slotIdx>>3 (= q*32 + (t>>3)),
  // slot s = t&7, logical chunk c = s ^ (r&7)  (q-invariant since 32|q*32).
  // c<4 -> A chunk c ; c>=4 -> B chunk c-4.
  const int rr = t >> 3;                       // 0..31
  const int cc = (t & 7) ^ (rr & 7);           // logical chunk 0..7
  const unsigned short* sbase =
      ((cc < 4) ? gA : gB) + (size_t)rr * DIM + (cc & 3) * 8;

  floatx4 acc[4][4];
#pragma unroll
  for (int i = 0; i < 4; ++i)
#pragma unroll
    for (int j = 0; j < 4; ++j) acc[i][j] = floatx4{0.f, 0.f, 0.f, 0.f};

  const int mrow = lane & 15;        // fragment row select
  const int hi   = lane >> 4;        // k quad 0..3
  const int rk   = mrow & 7;         // row&7 for all fragment rows (16|mt*16)
  const int aoff = (hi ^ rk) << 3;         // A chunk hi  -> slot hi^rk
  const int boff = ((4 + hi) ^ rk) << 3;   // B chunk hi  -> slot (4+hi)^rk

  for (int k0 = 0; k0 < DIM; k0 += 32) {
    __syncthreads();
#pragma unroll
    for (int q = 0; q < 4; ++q)
      gload16(sbase + (size_t)q * 32 * DIM + k0, lAB + (q * 256 + t) * 8);
    __syncthreads();   // compiler inserts vmcnt(0) drain here

    bf16x8 af[4], bq[4];
#pragma unroll
    for (int mt = 0; mt < 4; ++mt)
      af[mt] = *reinterpret_cast<const bf16x8*>(&lAB[(wm * 64 + mt * 16 + mrow) * 64 + aoff]);
#pragma unroll
    for (int nt = 0; nt < 4; ++nt)
      bq[nt] = *reinterpret_cast<const bf16x8*>(&lAB[(wn * 64 + nt * 16 + mrow) * 64 + boff]);
#pragma unroll
    for (int mt = 0; mt < 4; ++mt)
#pragma unroll
      for (int nt = 0; nt < 4; ++nt)
        acc[mt][nt] = __builtin_amdgcn_mfma_f32_16x16x32_bf16(af[mt], bq[nt], acc[mt][nt], 0, 0, 0);
  }

  if (t < 128) dl[t] = 0.f; else cl[t - 128] = 0.f;
  __syncthreads();

  // exp in-place: acc now holds e = exp(sim/T)
#pragma unroll
  for (int mt = 0; mt < 4; ++mt)
#pragma unroll
    for (int nt = 0; nt < 4; ++nt)
#pragma unroll
      for (int r = 0; r < 4; ++r)
        acc[mt][nt][r] = __expf(acc[mt][nt][r] * INV_T);

  // row-sums: C/D layout (16x16): col = lane&15, row = (lane>>4)*4 + reg [m89]
#pragma unroll
  for (int mt = 0; mt < 4; ++mt) {
#pragma unroll
    for (int r = 0; r < 4; ++r) {
      float s = acc[mt][0][r] + acc[mt][1][r] + acc[mt][2][r] + acc[mt][3][r];
      s += __shfl_xor(s, 1, 64);
      s += __shfl_xor(s, 2, 64);
      s += __shfl_xor(s, 4, 64);
      s += __shfl_xor(s, 8, 64);
      if ((lane & 15) == 0)
        atomicAdd(&dl[wm * 64 + mt * 16 + (lane >> 4) * 4 + r], s);
    }
  }

  // col-sums (mirror rows), off-diag tiles only
  if (offdiag) {
#pragma unroll
    for (int nt = 0; nt < 4; ++nt) {
      float c = 0.f;
#pragma unroll
      for (int mt = 0; mt < 4; ++mt)
#pragma unroll
        for (int r = 0; r < 4; ++r) c += acc[mt][nt][r];
      c += __shfl_xor(c, 16, 64);
      c += __shfl_xor(c, 32, 64);
      if ((lane >> 4) == 0)
        atomicAdd(&cl[wn * 64 + nt * 16 + (lane & 15)], c);
    }
  }
  __syncthreads();
  if (t < 128) {
    atomicAdd(&denom[brow * 128 + t], dl[t]);
    if (offdiag) atomicAdd(&denom[bcol * 128 + t], cl[t]);
  }
  // __syncthreads drains vmcnt(0): this block's device-scope denom atomics
  // have completed at the coherence point before the counter bump below.
  __syncthreads();
  if (t == 0)
    is_last = (__hip_atomic_fetch_add(cnt, 1u, __ATOMIC_RELAXED,
                                      __HIP_MEMORY_SCOPE_AGENT) == NTILES - 1)
                  ? 1u : 0u;
  __syncthreads();
  if (is_last) {
    float v = 0.f;
#pragma unroll
    for (int i = 0; i < TWON / 256; ++i) {
      float d = __hip_atomic_load(&denom[i * 256 + t], __ATOMIC_RELAXED,
                                  __HIP_MEMORY_SCOPE_AGENT);
      v += __logf(d - EXP_DIAG);
    }
    float p = 0.f;
#pragma unroll
    for (int i = 0; i < NROWS / 256; ++i)
      p += pos[i * 256 + t];
    v -= 4.0f * p;
#pragma unroll
    for (int o = 32; o; o >>= 1) v += __shfl_down(v, o, 64);
    if ((t & 63) == 0) dl[t >> 6] = v;
    __syncthreads();
    if (t == 0)
      out[0] = (dl[0] + dl[1] + dl[2] + dl[3]) * (1.0f / 8192.0f);
  }
}

extern "C" void kernel_launch(void* const* d_in, const int* in_sizes, int n_in,
                              void* d_out, int out_size, void* d_ws, size_t ws_size,
                              hipStream_t stream) {
  const float* emb_i = (const float*)d_in[0];
  const float* emb_j = (const float*)d_in[1];
  float* out = (float*)d_out;

  unsigned short* reps = (unsigned short*)d_ws;                    // 16.78 MB bf16
  float* denom = (float*)((char*)d_ws + (size_t)TWON * DIM * 2);   // 32 KB
  float* pos   = denom + TWON;                                     // 16 KB
  unsigned int* cnt = (unsigned int*)(pos + NROWS);

  normpos_kernel<<<NROWS, 256, 0, stream>>>(emb_i, emb_j, reps, denom, pos, cnt);
  simsum_kernel<<<NTILES, 256, 0, stream>>>(reps, denom, pos, cnt, out);
}

// Round 6
// 175.304 us; speedup vs baseline: 1.5921x; 1.0382x over previous
//
#include <hip/hip_runtime.h>
#include <hip/hip_fp8.h>
#include <cstdint>
#include <cstddef>

#define NROWS 4096
#define DIM   1024            // elements per row; also BYTES per fp8 row
#define TWON  8192
#define INV_T 2.0f
// exp(2.0) = exp(sim_rr / T) for the masked diagonal (rows are unit-norm)
#define EXP_DIAG 7.38905609893065f
#define NTILES (64 * 65 / 2)
#define SCALE1 0x7F7F7F7F     // 4x E8M0 unity scales (127 -> 2^0)

typedef float floatx4 __attribute__((ext_vector_type(4)));
typedef int   intx4   __attribute__((ext_vector_type(4)));
typedef int   intx8   __attribute__((ext_vector_type(8)));

__device__ __forceinline__ void gload16(const uint8_t* g, uint8_t* l) {
  __builtin_amdgcn_global_load_lds(
      (const __attribute__((address_space(1))) void*)g,
      (__attribute__((address_space(3))) void*)l,
      16, 0, 0);
}

__device__ __forceinline__ uint32_t pack_fp8x4(float x, float y, float z, float w) {
  __hip_fp8_e4m3 a(x), b(y), c(z), d(w);   // OCP e4m3fn, RNE+sat
  return (uint32_t)a.__x | ((uint32_t)b.__x << 8) |
         ((uint32_t)c.__x << 16) | ((uint32_t)d.__x << 24);
}

// -- kernel 1: normalize rows k and k+N -> fp8 reps, fp32 pos dot, zero denom -
__global__ __launch_bounds__(256) void normpos_kernel(
    const float* __restrict__ emb_i, const float* __restrict__ emb_j,
    uint8_t* __restrict__ reps, float* __restrict__ denom,
    float* __restrict__ pos, unsigned int* __restrict__ cnt) {
  const int k = blockIdx.x;                   // 0..4095 (pair index)
  const int t = threadIdx.x;                  // 256 threads, 4 floats per row
  if (k < 32) denom[k * 256 + t] = 0.f;       // stream-ordered before simsum
  if (k == 32 && t == 0) *cnt = 0u;           // completion counter for simsum

  float4 vi = reinterpret_cast<const float4*>(emb_i + (size_t)k * DIM)[t];
  float4 vj = reinterpret_cast<const float4*>(emb_j + (size_t)k * DIM)[t];
  float ssi = vi.x * vi.x + vi.y * vi.y + vi.z * vi.z + vi.w * vi.w;
  float ssj = vj.x * vj.x + vj.y * vj.y + vj.z * vj.z + vj.w * vj.w;
  float dot = vi.x * vj.x + vi.y * vj.y + vi.z * vj.z + vi.w * vj.w;
#pragma unroll
  for (int o = 32; o; o >>= 1) {
    ssi += __shfl_down(ssi, o, 64);
    ssj += __shfl_down(ssj, o, 64);
    dot += __shfl_down(dot, o, 64);
  }
  __shared__ float red[3][4];
  if ((t & 63) == 0) {
    red[0][t >> 6] = ssi; red[1][t >> 6] = ssj; red[2][t >> 6] = dot;
  }
  __syncthreads();
  float ti = red[0][0] + red[0][1] + red[0][2] + red[0][3];
  float tj = red[1][0] + red[1][1] + red[1][2] + red[1][3];
  float invi = 1.0f / fmaxf(sqrtf(ti), 1e-12f);
  float invj = 1.0f / fmaxf(sqrtf(tj), 1e-12f);
  uint32_t wi = pack_fp8x4(vi.x * invi, vi.y * invi, vi.z * invi, vi.w * invi);
  uint32_t wj = pack_fp8x4(vj.x * invj, vj.y * invj, vj.z * invj, vj.w * invj);
  reinterpret_cast<uint32_t*>(reps + (size_t)k * DIM)[t] = wi;
  reinterpret_cast<uint32_t*>(reps + (size_t)(k + NROWS) * DIM)[t] = wj;
  if (t == 0) {
    float td = red[2][0] + red[2][1] + red[2][2] + red[2][3];
    pos[k] = td * invi * invj;   // cosine of the positive pair, fp32 exact
  }
}

// ---- kernel 2: fused sim-GEMM (MX-fp8) + exp + row/col sums, upper tri -----
// C-tile 128x128, 4 waves 2x2, each wave 4x4 grid of 16x16x128 scaled MFMAs,
// BK=128 (one K-chunk per MFMA) -> only 8 staging barriers.
// LDS rows are 128 B (32 banks, row-independent); 16 B chunks XOR-swizzled
// by row&7 so fragment reads hit 2 lanes/bank (free per m136).
// A-frag layout assumed: A[m=lane&15][k=(lane>>4)*32 + j], j=0..31 bytes
// (natural extension of verified 16x16x32 bf16 quad*8+j). Unity E8M0 scales.
__global__ __launch_bounds__(256) void simsum_kernel(
    const uint8_t* __restrict__ reps, float* __restrict__ denom,
    const float* __restrict__ pos, unsigned int* __restrict__ cnt,
    float* __restrict__ out) {
  __shared__ __align__(16) uint8_t lA[128 * 128];  // 16 KB
  __shared__ __align__(16) uint8_t lB[128 * 128];  // 16 KB
  __shared__ float dl[128];   // row-side partial sums
  __shared__ float cl[128];   // col-side partial sums
  __shared__ unsigned int is_last;

  const int t    = threadIdx.x;
  const int lane = t & 63;
  const int wave = t >> 6;
  const int wm   = wave >> 1;      // wave row 0..1
  const int wn   = wave & 1;       // wave col 0..1

  // triangular unranking: f(b) = b*(129-b)/2 tiles before block-row b
  const int idx = blockIdx.x;      // 0..2079
  int brow = (int)(64.5f - sqrtf(64.5f * 64.5f - 2.0f * (float)idx));
  if (brow > 63) brow = 63;
  if (brow < 0) brow = 0;
  while ((brow + 1) * (129 - (brow + 1)) / 2 <= idx) ++brow;
  while (brow * (129 - brow) / 2 > idx) --brow;
  const int bcol = brow + (idx - brow * (129 - brow) / 2);
  const bool offdiag = (brow != bcol);

  const uint8_t* gA = reps + (size_t)brow * 128 * DIM;
  const uint8_t* gB = reps + (size_t)bcol * 128 * DIM;

  // staging: thread t -> row q*32 + (t>>3), slot t&7; logical chunk = slot^(row&7)
  const int rr  = t >> 3;                      // 0..31
  const int swz = ((t & 7) ^ (rr & 7)) << 4;   // source byte offset of chunk
  // LDS dst byte = q*4096 + t*16  (wave-uniform base + lane*16)

  floatx4 acc[4][4];
#pragma unroll
  for (int i = 0; i < 4; ++i)
#pragma unroll
    for (int j = 0; j < 4; ++j) acc[i][j] = floatx4{0.f, 0.f, 0.f, 0.f};

  const int mrow = lane & 15;        // fragment row select
  const int quad = lane >> 4;        // k block 0..3 (32 bytes each)
  const int rk   = mrow & 7;         // swizzle key (16 | all row bases)
  const int sl0  = (((quad << 1)    ) ^ rk) << 4;  // first 16B chunk slot
  const int sl1  = (((quad << 1) | 1) ^ rk) << 4;  // second 16B chunk slot

  for (int k0 = 0; k0 < DIM; k0 += 128) {
    __syncthreads();
#pragma unroll
    for (int q = 0; q < 4; ++q) {
      gload16(gA + (size_t)(q * 32 + rr) * DIM + k0 + swz, lA + q * 4096 + t * 16);
      gload16(gB + (size_t)(q * 32 + rr) * DIM + k0 + swz, lB + q * 4096 + t * 16);
    }
    __syncthreads();   // compiler inserts vmcnt(0) drain here

    union { intx8 v8; intx4 v4[2]; } fa[4], fb[4];
#pragma unroll
    for (int mt = 0; mt < 4; ++mt) {
      const uint8_t* p = lA + (wm * 64 + mt * 16 + mrow) * 128;
      fa[mt].v4[0] = *reinterpret_cast<const intx4*>(p + sl0);
      fa[mt].v4[1] = *reinterpret_cast<const intx4*>(p + sl1);
    }
#pragma unroll
    for (int nt = 0; nt < 4; ++nt) {
      const uint8_t* p = lB + (wn * 64 + nt * 16 + mrow) * 128;
      fb[nt].v4[0] = *reinterpret_cast<const intx4*>(p + sl0);
      fb[nt].v4[1] = *reinterpret_cast<const intx4*>(p + sl1);
    }
#pragma unroll
    for (int mt = 0; mt < 4; ++mt)
#pragma unroll
      for (int nt = 0; nt < 4; ++nt)
        acc[mt][nt] = __builtin_amdgcn_mfma_scale_f32_16x16x128_f8f6f4(
            fa[mt].v8, fb[nt].v8, acc[mt][nt], 0, 0, 0, SCALE1, 0, SCALE1);
  }

  if (t < 128) dl[t] = 0.f; else cl[t - 128] = 0.f;
  __syncthreads();

  // exp in-place: acc now holds e = exp(sim/T)
#pragma unroll
  for (int mt = 0; mt < 4; ++mt)
#pragma unroll
    for (int nt = 0; nt < 4; ++nt)
#pragma unroll
      for (int r = 0; r < 4; ++r)
        acc[mt][nt][r] = __expf(acc[mt][nt][r] * INV_T);

  // row-sums: C/D layout (16x16, shape-determined): col=lane&15, row=quad*4+r
#pragma unroll
  for (int mt = 0; mt < 4; ++mt) {
#pragma unroll
    for (int r = 0; r < 4; ++r) {
      float s = acc[mt][0][r] + acc[mt][1][r] + acc[mt][2][r] + acc[mt][3][r];
      s += __shfl_xor(s, 1, 64);
      s += __shfl_xor(s, 2, 64);
      s += __shfl_xor(s, 4, 64);
      s += __shfl_xor(s, 8, 64);
      if ((lane & 15) == 0)
        atomicAdd(&dl[wm * 64 + mt * 16 + quad * 4 + r], s);
    }
  }

  // col-sums (mirror rows), off-diag tiles only
  if (offdiag) {
#pragma unroll
    for (int nt = 0; nt < 4; ++nt) {
      float c = 0.f;
#pragma unroll
      for (int mt = 0; mt < 4; ++mt)
#pragma unroll
        for (int r = 0; r < 4; ++r) c += acc[mt][nt][r];
      c += __shfl_xor(c, 16, 64);
      c += __shfl_xor(c, 32, 64);
      if (quad == 0)
        atomicAdd(&cl[wn * 64 + nt * 16 + mrow], c);
    }
  }
  __syncthreads();
  if (t < 128) {
    atomicAdd(&denom[brow * 128 + t], dl[t]);
    if (offdiag) atomicAdd(&denom[bcol * 128 + t], cl[t]);
  }
  // __syncthreads drains vmcnt(0): this block's device-scope denom atomics
  // are complete at the coherence point before the counter bump below.
  __syncthreads();
  if (t == 0)
    is_last = (__hip_atomic_fetch_add(cnt, 1u, __ATOMIC_RELAXED,
                                      __HIP_MEMORY_SCOPE_AGENT) == NTILES - 1)
                  ? 1u : 0u;
  __syncthreads();
  if (is_last) {
    float v = 0.f;
#pragma unroll
    for (int i = 0; i < TWON / 256; ++i) {
      float d = __hip_atomic_load(&denom[i * 256 + t], __ATOMIC_RELAXED,
                                  __HIP_MEMORY_SCOPE_AGENT);
      v += __logf(d - EXP_DIAG);
    }
    float p = 0.f;
#pragma unroll
    for (int i = 0; i < NROWS / 256; ++i)
      p += pos[i * 256 + t];
    v -= 4.0f * p;
#pragma unroll
    for (int o = 32; o; o >>= 1) v += __shfl_down(v, o, 64);
    if ((t & 63) == 0) dl[t >> 6] = v;
    __syncthreads();
    if (t == 0)
      out[0] = (dl[0] + dl[1] + dl[2] + dl[3]) * (1.0f / 8192.0f);
  }
}

extern "C" void kernel_launch(void* const* d_in, const int* in_sizes, int n_in,
                              void* d_out, int out_size, void* d_ws, size_t ws_size,
                              hipStream_t stream) {
  const float* emb_i = (const float*)d_in[0];
  const float* emb_j = (const float*)d_in[1];
  float* out = (float*)d_out;

  uint8_t* reps = (uint8_t*)d_ws;                                  // 8.39 MB fp8
  float* denom  = (float*)((char*)d_ws + (size_t)TWON * DIM);      // 32 KB
  float* pos    = denom + TWON;                                    // 16 KB
  unsigned int* cnt = (unsigned int*)(pos + NROWS);

  normpos_kernel<<<NROWS, 256, 0, stream>>>(emb_i, emb_j, reps, denom, pos, cnt);
  simsum_kernel<<<NTILES, 256, 0, stream>>>(reps, denom, pos, cnt, out);
}

// Round 7
// 144.124 us; speedup vs baseline: 1.9366x; 1.2163x over previous
//
#include <hip/hip_runtime.h>
#include <hip/hip_fp8.h>
#include <cstdint>
#include <cstddef>

#define NROWS 4096
#define DIM   1024            // elements per row; also BYTES per fp8 row
#define TWON  8192
#define INV_T 2.0f
// exp(2.0) = exp(sim_rr / T) for the masked diagonal (rows are unit-norm)
#define EXP_DIAG 7.38905609893065f
#define NTILES (64 * 65 / 2)
#define SCALE1 0x7F7F7F7F     // 4x E8M0 unity scales (127 -> 2^0)

typedef float floatx4 __attribute__((ext_vector_type(4)));
typedef int   intx4   __attribute__((ext_vector_type(4)));
typedef int   intx8   __attribute__((ext_vector_type(8)));

union F8 { intx8 v8; intx4 v4[2]; };

__device__ __forceinline__ void gload16(const uint8_t* g, uint8_t* l) {
  __builtin_amdgcn_global_load_lds(
      (const __attribute__((address_space(1))) void*)g,
      (__attribute__((address_space(3))) void*)l,
      16, 0, 0);
}

__device__ __forceinline__ uint32_t pack_fp8x4(float x, float y, float z, float w) {
  __hip_fp8_e4m3 a(x), b(y), c(z), d(w);   // OCP e4m3fn, RNE+sat
  return (uint32_t)a.__x | ((uint32_t)b.__x << 8) |
         ((uint32_t)c.__x << 16) | ((uint32_t)d.__x << 24);
}

// -- kernel 1: normalize rows k and k+N -> fp8 reps, fp32 pos dot, zero denom -
__global__ __launch_bounds__(256) void normpos_kernel(
    const float* __restrict__ emb_i, const float* __restrict__ emb_j,
    uint8_t* __restrict__ reps, float* __restrict__ denom,
    float* __restrict__ pos, unsigned int* __restrict__ cnt) {
  const int k = blockIdx.x;                   // 0..4095 (pair index)
  const int t = threadIdx.x;                  // 256 threads, 4 floats per row
  if (k < 32) denom[k * 256 + t] = 0.f;       // stream-ordered before simsum
  if (k == 32 && t == 0) *cnt = 0u;           // completion counter for simsum

  float4 vi = reinterpret_cast<const float4*>(emb_i + (size_t)k * DIM)[t];
  float4 vj = reinterpret_cast<const float4*>(emb_j + (size_t)k * DIM)[t];
  float ssi = vi.x * vi.x + vi.y * vi.y + vi.z * vi.z + vi.w * vi.w;
  float ssj = vj.x * vj.x + vj.y * vj.y + vj.z * vj.z + vj.w * vj.w;
  float dot = vi.x * vj.x + vi.y * vj.y + vi.z * vj.z + vi.w * vj.w;
#pragma unroll
  for (int o = 32; o; o >>= 1) {
    ssi += __shfl_down(ssi, o, 64);
    ssj += __shfl_down(ssj, o, 64);
    dot += __shfl_down(dot, o, 64);
  }
  __shared__ float red[3][4];
  if ((t & 63) == 0) {
    red[0][t >> 6] = ssi; red[1][t >> 6] = ssj; red[2][t >> 6] = dot;
  }
  __syncthreads();
  float ti = red[0][0] + red[0][1] + red[0][2] + red[0][3];
  float tj = red[1][0] + red[1][1] + red[1][2] + red[1][3];
  float invi = 1.0f / fmaxf(sqrtf(ti), 1e-12f);
  float invj = 1.0f / fmaxf(sqrtf(tj), 1e-12f);
  uint32_t wi = pack_fp8x4(vi.x * invi, vi.y * invi, vi.z * invi, vi.w * invi);
  uint32_t wj = pack_fp8x4(vj.x * invj, vj.y * invj, vj.z * invj, vj.w * invj);
  reinterpret_cast<uint32_t*>(reps + (size_t)k * DIM)[t] = wi;
  reinterpret_cast<uint32_t*>(reps + (size_t)(k + NROWS) * DIM)[t] = wj;
  if (t == 0) {
    float td = red[2][0] + red[2][1] + red[2][2] + red[2][3];
    pos[k] = td * invi * invj;   // cosine of the positive pair, fp32 exact
  }
}

// ---- kernel 2: fused sim-GEMM (MX-fp8) + exp + row/col sums, upper tri -----
// C-tile 128x128, 4 waves 2x2, each wave 4x4 grid of 16x16x128 scaled MFMAs,
// BK=128 -> 8 staging iterations. __launch_bounds__(256,4) caps VGPR at 128
// so 4 blocks/CU stay resident (round 6: 252 VGPR -> 2 blocks/CU -> 10% occ).
// LDS rows are 128 B; each lane's 32 fragment bytes are CONTIGUOUS at 32B
// slot (quad ^ (row&3)) -> within any 8-lane phase: 4 slots x 2 lanes at
// identical addresses (broadcast) -> conflict-free and robust to re-splitting.
// A-frag layout A[m=lane&15][k=quad*32+j] verified exact in round 6.
__global__ __launch_bounds__(256, 4) void simsum_kernel(
    const uint8_t* __restrict__ reps, float* __restrict__ denom,
    const float* __restrict__ pos, unsigned int* __restrict__ cnt,
    float* __restrict__ out) {
  __shared__ __align__(16) uint8_t lA[128 * 128];  // 16 KB
  __shared__ __align__(16) uint8_t lB[128 * 128];  // 16 KB
  __shared__ float dl[128];   // row-side partial sums
  __shared__ float cl[128];   // col-side partial sums
  __shared__ unsigned int is_last;

  const int t    = threadIdx.x;
  const int lane = t & 63;
  const int wave = t >> 6;
  const int wm   = wave >> 1;      // wave row 0..1
  const int wn   = wave & 1;       // wave col 0..1

  // triangular unranking: f(b) = b*(129-b)/2 tiles before block-row b
  const int idx = blockIdx.x;      // 0..2079
  int brow = (int)(64.5f - sqrtf(64.5f * 64.5f - 2.0f * (float)idx));
  if (brow > 63) brow = 63;
  if (brow < 0) brow = 0;
  while ((brow + 1) * (129 - (brow + 1)) / 2 <= idx) ++brow;
  while (brow * (129 - brow) / 2 > idx) --brow;
  const int bcol = brow + (idx - brow * (129 - brow) / 2);
  const bool offdiag = (brow != bcol);

  const uint8_t* gA = reps + (size_t)brow * 128 * DIM;
  const uint8_t* gB = reps + (size_t)bcol * 128 * DIM;

  // staging: thread t -> row q*32 + rr (rr = t>>3), 16B half-slot s16 = t&7.
  // logical 32B chunk c32 = (s16>>1) ^ (rr&3); source byte = c32*32+(s16&1)*16.
  const int rr  = t >> 3;
  const int swz = ((((t >> 1) & 3) ^ (rr & 3)) << 5) | ((t & 1) << 4);
  // LDS dst byte = q*4096 + t*16  (wave-uniform base + lane*16)

  floatx4 acc[4][4];
#pragma unroll
  for (int i = 0; i < 4; ++i)
#pragma unroll
    for (int j = 0; j < 4; ++j) acc[i][j] = floatx4{0.f, 0.f, 0.f, 0.f};

  const int mrow = lane & 15;        // fragment row select
  const int quad = lane >> 4;        // k block 0..3 (32 bytes each)
  const int soff = (quad ^ (mrow & 3)) << 5;   // 32B slot of this lane's chunk

#pragma unroll 1
  for (int k0 = 0; k0 < DIM; k0 += 128) {
    __syncthreads();
#pragma unroll
    for (int q = 0; q < 4; ++q) {
      gload16(gA + (size_t)(q * 32 + rr) * DIM + k0 + swz, lA + q * 4096 + t * 16);
      gload16(gB + (size_t)(q * 32 + rr) * DIM + k0 + swz, lB + q * 4096 + t * 16);
    }
    __syncthreads();   // compiler inserts vmcnt(0) drain here

    F8 fb[4];
#pragma unroll
    for (int nt = 0; nt < 4; ++nt) {
      const uint8_t* p = lB + (wn * 64 + nt * 16 + mrow) * 128 + soff;
      fb[nt].v4[0] = *reinterpret_cast<const intx4*>(p);
      fb[nt].v4[1] = *reinterpret_cast<const intx4*>(p + 16);
    }
#pragma unroll
    for (int mt = 0; mt < 4; ++mt) {
      F8 fa;
      const uint8_t* p = lA + (wm * 64 + mt * 16 + mrow) * 128 + soff;
      fa.v4[0] = *reinterpret_cast<const intx4*>(p);
      fa.v4[1] = *reinterpret_cast<const intx4*>(p + 16);
#pragma unroll
      for (int nt = 0; nt < 4; ++nt)
        acc[mt][nt] = __builtin_amdgcn_mfma_scale_f32_16x16x128_f8f6f4(
            fa.v8, fb[nt].v8, acc[mt][nt], 0, 0, 0, SCALE1, 0, SCALE1);
    }
  }

  if (t < 128) dl[t] = 0.f; else cl[t - 128] = 0.f;
  __syncthreads();

  // exp in-place: acc now holds e = exp(sim/T)
#pragma unroll
  for (int mt = 0; mt < 4; ++mt)
#pragma unroll
    for (int nt = 0; nt < 4; ++nt)
#pragma unroll
      for (int r = 0; r < 4; ++r)
        acc[mt][nt][r] = __expf(acc[mt][nt][r] * INV_T);

  // row-sums: C/D layout (16x16, shape-determined): col=lane&15, row=quad*4+r
#pragma unroll
  for (int mt = 0; mt < 4; ++mt) {
#pragma unroll
    for (int r = 0; r < 4; ++r) {
      float s = acc[mt][0][r] + acc[mt][1][r] + acc[mt][2][r] + acc[mt][3][r];
      s += __shfl_xor(s, 1, 64);
      s += __shfl_xor(s, 2, 64);
      s += __shfl_xor(s, 4, 64);
      s += __shfl_xor(s, 8, 64);
      if ((lane & 15) == 0)
        atomicAdd(&dl[wm * 64 + mt * 16 + quad * 4 + r], s);
    }
  }

  // col-sums (mirror rows), off-diag tiles only
  if (offdiag) {
#pragma unroll
    for (int nt = 0; nt < 4; ++nt) {
      float c = 0.f;
#pragma unroll
      for (int mt = 0; mt < 4; ++mt)
#pragma unroll
        for (int r = 0; r < 4; ++r) c += acc[mt][nt][r];
      c += __shfl_xor(c, 16, 64);
      c += __shfl_xor(c, 32, 64);
      if (quad == 0)
        atomicAdd(&cl[wn * 64 + nt * 16 + mrow], c);
    }
  }
  __syncthreads();
  if (t < 128) {
    atomicAdd(&denom[brow * 128 + t], dl[t]);
    if (offdiag) atomicAdd(&denom[bcol * 128 + t], cl[t]);
  }
  // __syncthreads drains vmcnt(0): this block's device-scope denom atomics
  // are complete at the coherence point before the counter bump below.
  __syncthreads();
  if (t == 0)
    is_last = (__hip_atomic_fetch_add(cnt, 1u, __ATOMIC_RELAXED,
                                      __HIP_MEMORY_SCOPE_AGENT) == NTILES - 1)
                  ? 1u : 0u;
  __syncthreads();
  if (is_last) {
    float v = 0.f;
#pragma unroll
    for (int i = 0; i < TWON / 256; ++i) {
      float d = __hip_atomic_load(&denom[i * 256 + t], __ATOMIC_RELAXED,
                                  __HIP_MEMORY_SCOPE_AGENT);
      v += __logf(d - EXP_DIAG);
    }
    float p = 0.f;
#pragma unroll
    for (int i = 0; i < NROWS / 256; ++i)
      p += pos[i * 256 + t];
    v -= 4.0f * p;
#pragma unroll
    for (int o = 32; o; o >>= 1) v += __shfl_down(v, o, 64);
    if ((t & 63) == 0) dl[t >> 6] = v;
    __syncthreads();
    if (t == 0)
      out[0] = (dl[0] + dl[1] + dl[2] + dl[3]) * (1.0f / 8192.0f);
  }
}

extern "C" void kernel_launch(void* const* d_in, const int* in_sizes, int n_in,
                              void* d_out, int out_size, void* d_ws, size_t ws_size,
                              hipStream_t stream) {
  const float* emb_i = (const float*)d_in[0];
  const float* emb_j = (const float*)d_in[1];
  float* out = (float*)d_out;

  uint8_t* reps = (uint8_t*)d_ws;                                  // 8.39 MB fp8
  float* denom  = (float*)((char*)d_ws + (size_t)TWON * DIM);      // 32 KB
  float* pos    = denom + TWON;                                    // 16 KB
  unsigned int* cnt = (unsigned int*)(pos + NROWS);

  normpos_kernel<<<NROWS, 256, 0, stream>>>(emb_i, emb_j, reps, denom, pos, cnt);
  simsum_kernel<<<NTILES, 256, 0, stream>>>(reps, denom, pos, cnt, out);
}

// Round 8
// 140.268 us; speedup vs baseline: 1.9898x; 1.0275x over previous
//
#include <hip/hip_runtime.h>
#include <hip/hip_fp8.h>
#include <cstdint>
#include <cstddef>

#define NROWS 4096
#define DIM   1024            // elements per row; also BYTES per fp8 row
#define TWON  8192
#define INV_T 2.0f
// exp(2.0) = exp(sim_rr / T) for the masked diagonal (rows are unit-norm)
#define EXP_DIAG 7.38905609893065f
#define NT2   1056            // # of 256x128 tiles covering the upper triangle
#define SCALE1 0x7F7F7F7F     // 4x E8M0 unity scales (127 -> 2^0)

typedef float floatx4 __attribute__((ext_vector_type(4)));
typedef int   intx4   __attribute__((ext_vector_type(4)));
typedef int   intx8   __attribute__((ext_vector_type(8)));

union F8 { intx8 v8; intx4 v4[2]; };

__device__ __forceinline__ void gload16(const uint8_t* g, uint8_t* l) {
  __builtin_amdgcn_global_load_lds(
      (const __attribute__((address_space(1))) void*)g,
      (__attribute__((address_space(3))) void*)l,
      16, 0, 0);
}

__device__ __forceinline__ uint32_t pack_fp8x4(float x, float y, float z, float w) {
  __hip_fp8_e4m3 a(x), b(y), c(z), d(w);   // OCP e4m3fn, RNE+sat
  return (uint32_t)a.__x | ((uint32_t)b.__x << 8) |
         ((uint32_t)c.__x << 16) | ((uint32_t)d.__x << 24);
}

// -- kernel 1: normalize -> fp8 reps, fp32 pos dot, zero denom/cnt ------------
// 512 blocks x 8 pairs each (round 7: 4096 tiny blocks cost ~40us dispatch).
__global__ __launch_bounds__(256) void normpos_kernel(
    const float* __restrict__ emb_i, const float* __restrict__ emb_j,
    uint8_t* __restrict__ reps, float* __restrict__ denom,
    float* __restrict__ pos, unsigned int* __restrict__ cnt) {
  const int t = threadIdx.x;                  // 256 threads, 4 floats per row
  if (blockIdx.x < 32) denom[blockIdx.x * 256 + t] = 0.f;
  if (blockIdx.x == 32 && t == 0) *cnt = 0u;

  __shared__ float red[3][4];
  for (int p = 0; p < 8; ++p) {
    const int k = blockIdx.x * 8 + p;         // 0..4095 (pair index)
    float4 vi = reinterpret_cast<const float4*>(emb_i + (size_t)k * DIM)[t];
    float4 vj = reinterpret_cast<const float4*>(emb_j + (size_t)k * DIM)[t];
    float ssi = vi.x * vi.x + vi.y * vi.y + vi.z * vi.z + vi.w * vi.w;
    float ssj = vj.x * vj.x + vj.y * vj.y + vj.z * vj.z + vj.w * vj.w;
    float dot = vi.x * vj.x + vi.y * vj.y + vi.z * vj.z + vi.w * vj.w;
#pragma unroll
    for (int o = 32; o; o >>= 1) {
      ssi += __shfl_down(ssi, o, 64);
      ssj += __shfl_down(ssj, o, 64);
      dot += __shfl_down(dot, o, 64);
    }
    __syncthreads();   // previous iteration's red reads complete
    if ((t & 63) == 0) {
      red[0][t >> 6] = ssi; red[1][t >> 6] = ssj; red[2][t >> 6] = dot;
    }
    __syncthreads();
    float ti = red[0][0] + red[0][1] + red[0][2] + red[0][3];
    float tj = red[1][0] + red[1][1] + red[1][2] + red[1][3];
    float invi = 1.0f / fmaxf(sqrtf(ti), 1e-12f);
    float invj = 1.0f / fmaxf(sqrtf(tj), 1e-12f);
    uint32_t wi = pack_fp8x4(vi.x * invi, vi.y * invi, vi.z * invi, vi.w * invi);
    uint32_t wj = pack_fp8x4(vj.x * invj, vj.y * invj, vj.z * invj, vj.w * invj);
    reinterpret_cast<uint32_t*>(reps + (size_t)k * DIM)[t] = wi;
    reinterpret_cast<uint32_t*>(reps + (size_t)(k + NROWS) * DIM)[t] = wj;
    if (t == 0) {
      float td = red[2][0] + red[2][1] + red[2][2] + red[2][3];
      pos[k] = td * invi * invj;   // cosine of the positive pair, fp32 exact
    }
  }
}

// ---- kernel 2: fused sim-GEMM (MX-fp8) + exp + row/col sums, upper tri -----
// C-tile 256x128 (rows bm*256.., cols bn*128..), 512 threads = 8 waves (4x2),
// each wave 4x4 grid of 16x16x128 scaled MFMAs, BK=128 -> 8 staging iters.
// Triangle at 256-granularity: bm in [0,32), bn in [2bm,64). The bn==2bm
// tile's lower 128-half is below-diagonal -> masked out (wave-uniform).
// Verified (R6/R7): A-frag A[m=lane&15][k=quad*32+j]; 32B-slot XOR swizzle
// (key=row&3) conflict-free; C/D col=lane&15,row=quad*4+reg.
__global__ __launch_bounds__(512, 4) void simsum_kernel(
    const uint8_t* __restrict__ reps, float* __restrict__ denom,
    const float* __restrict__ pos, unsigned int* __restrict__ cnt,
    float* __restrict__ out) {
  __shared__ __align__(16) uint8_t lA[256 * 128];  // 32 KB
  __shared__ __align__(16) uint8_t lB[128 * 128];  // 16 KB
  __shared__ float dl[256];   // row-side partial sums
  __shared__ float cl[128];   // col-side partial sums
  __shared__ unsigned int is_last;

  const int t    = threadIdx.x;
  const int lane = t & 63;
  const int wave = t >> 6;         // 0..7
  const int wm   = wave >> 1;      // wave row 0..3 (64-row strip)
  const int wn   = wave & 1;       // wave col 0..1 (64-col strip)

  // unrank: f(bm) = bm*(65-bm) tiles before block-row bm
  const int idx = blockIdx.x;      // 0..1055
  int bm = (int)(32.5f - sqrtf(1056.25f - (float)idx));
  if (bm < 0) bm = 0;
  if (bm > 31) bm = 31;
  while (bm < 31 && (bm + 1) * (65 - (bm + 1)) <= idx) ++bm;
  while (bm > 0 && bm * (65 - bm) > idx) --bm;
  const int bn = 2 * bm + (idx - bm * (65 - bm));   // 2bm..63

  const uint8_t* gA = reps + (size_t)bm * 256 * DIM;
  const uint8_t* gB = reps + (size_t)bn * 128 * DIM;

  // staging: thread t -> row q*64 + rr (rr=t>>3), 16B half-slot s16=t&7.
  // 32B chunk c32 = (s16>>1)^(rr&3); src byte = c32*32 + (s16&1)*16.
  const int rr  = t >> 3;                                      // 0..63
  const int swz = ((((t >> 1) & 3) ^ (rr & 3)) << 5) | ((t & 1) << 4);

  floatx4 acc[4][4];
#pragma unroll
  for (int i = 0; i < 4; ++i)
#pragma unroll
    for (int j = 0; j < 4; ++j) acc[i][j] = floatx4{0.f, 0.f, 0.f, 0.f};

  const int mrow = lane & 15;        // fragment row select
  const int quad = lane >> 4;        // k block 0..3 (32 bytes each)
  const int soff = (quad ^ (mrow & 3)) << 5;   // 32B slot of this lane's chunk

#pragma unroll 1
  for (int k0 = 0; k0 < DIM; k0 += 128) {
    __syncthreads();
#pragma unroll
    for (int q = 0; q < 4; ++q)   // A: 256 rows
      gload16(gA + (size_t)(q * 64 + rr) * DIM + k0 + swz, lA + q * 8192 + t * 16);
#pragma unroll
    for (int q = 0; q < 2; ++q)   // B: 128 rows
      gload16(gB + (size_t)(q * 64 + rr) * DIM + k0 + swz, lB + q * 8192 + t * 16);
    __syncthreads();   // compiler inserts vmcnt(0) drain here

    F8 fb[4];
#pragma unroll
    for (int nt = 0; nt < 4; ++nt) {
      const uint8_t* p = lB + (wn * 64 + nt * 16 + mrow) * 128 + soff;
      fb[nt].v4[0] = *reinterpret_cast<const intx4*>(p);
      fb[nt].v4[1] = *reinterpret_cast<const intx4*>(p + 16);
    }
#pragma unroll
    for (int mt = 0; mt < 4; ++mt) {
      F8 fa;
      const uint8_t* p = lA + (wm * 64 + mt * 16 + mrow) * 128 + soff;
      fa.v4[0] = *reinterpret_cast<const intx4*>(p);
      fa.v4[1] = *reinterpret_cast<const intx4*>(p + 16);
#pragma unroll
      for (int nt = 0; nt < 4; ++nt)
        acc[mt][nt] = __builtin_amdgcn_mfma_scale_f32_16x16x128_f8f6f4(
            fa.v8, fb[nt].v8, acc[mt][nt], 0, 0, 0, SCALE1, 0, SCALE1);
    }
  }

  if (t < 256) dl[t] = 0.f;
  else if (t < 384) cl[t - 256] = 0.f;
  __syncthreads();

  // half-tile masks (wave-uniform): h = which 128-row half this wave is in
  const int  h       = wm >> 1;
  const int  r128    = 2 * bm + h;
  const bool skipAll = (r128 > bn);    // below-diagonal half (bn==2bm, h==1)
  const bool doCol   = (r128 < bn);    // strictly-above-diagonal half

  // exp in-place: acc now holds e = exp(sim/T)
#pragma unroll
  for (int mt = 0; mt < 4; ++mt)
#pragma unroll
    for (int nt = 0; nt < 4; ++nt)
#pragma unroll
      for (int r = 0; r < 4; ++r)
        acc[mt][nt][r] = __expf(acc[mt][nt][r] * INV_T);

  // row-sums: C/D layout (16x16): col=lane&15, row=quad*4+r
  if (!skipAll) {
#pragma unroll
    for (int mt = 0; mt < 4; ++mt) {
#pragma unroll
      for (int r = 0; r < 4; ++r) {
        float s = acc[mt][0][r] + acc[mt][1][r] + acc[mt][2][r] + acc[mt][3][r];
        s += __shfl_xor(s, 1, 64);
        s += __shfl_xor(s, 2, 64);
        s += __shfl_xor(s, 4, 64);
        s += __shfl_xor(s, 8, 64);
        if ((lane & 15) == 0)
          atomicAdd(&dl[wm * 64 + mt * 16 + quad * 4 + r], s);
      }
    }
  }

  // col-sums (mirror rows), strictly-off-diagonal halves only
  if (doCol) {
#pragma unroll
    for (int nt = 0; nt < 4; ++nt) {
      float c = 0.f;
#pragma unroll
      for (int mt = 0; mt < 4; ++mt)
#pragma unroll
        for (int r = 0; r < 4; ++r) c += acc[mt][nt][r];
      c += __shfl_xor(c, 16, 64);
      c += __shfl_xor(c, 32, 64);
      if (quad == 0)
        atomicAdd(&cl[wn * 64 + nt * 16 + mrow], c);
    }
  }
  __syncthreads();
  if (t < 256) {
    const bool rowOk = !((bn == 2 * bm) && (t >= 128));
    if (rowOk) atomicAdd(&denom[bm * 256 + t], dl[t]);
  } else if (t < 384 && bn > 2 * bm) {
    atomicAdd(&denom[bn * 128 + (t - 256)], cl[t - 256]);
  }
  // __syncthreads drains vmcnt(0): this block's device-scope denom atomics
  // are complete at the coherence point before the counter bump below.
  __syncthreads();
  if (t == 0)
    is_last = (__hip_atomic_fetch_add(cnt, 1u, __ATOMIC_RELAXED,
                                      __HIP_MEMORY_SCOPE_AGENT) == NT2 - 1)
                  ? 1u : 0u;
  __syncthreads();
  if (is_last) {
    float v = 0.f;
#pragma unroll
    for (int i = 0; i < TWON / 512; ++i) {
      float d = __hip_atomic_load(&denom[i * 512 + t], __ATOMIC_RELAXED,
                                  __HIP_MEMORY_SCOPE_AGENT);
      v += __logf(d - EXP_DIAG);
    }
    float p = 0.f;
#pragma unroll
    for (int i = 0; i < NROWS / 512; ++i)
      p += pos[i * 512 + t];
    v -= 4.0f * p;
#pragma unroll
    for (int o = 32; o; o >>= 1) v += __shfl_down(v, o, 64);
    if ((t & 63) == 0) dl[t >> 6] = v;
    __syncthreads();
    if (t == 0) {
      float tot = 0.f;
#pragma unroll
      for (int w = 0; w < 8; ++w) tot += dl[w];
      out[0] = tot * (1.0f / 8192.0f);
    }
  }
}

extern "C" void kernel_launch(void* const* d_in, const int* in_sizes, int n_in,
                              void* d_out, int out_size, void* d_ws, size_t ws_size,
                              hipStream_t stream) {
  const float* emb_i = (const float*)d_in[0];
  const float* emb_j = (const float*)d_in[1];
  float* out = (float*)d_out;

  uint8_t* reps = (uint8_t*)d_ws;                                  // 8.39 MB fp8
  float* denom  = (float*)((char*)d_ws + (size_t)TWON * DIM);      // 32 KB
  float* pos    = denom + TWON;                                    // 16 KB
  unsigned int* cnt = (unsigned int*)(pos + NROWS);

  normpos_kernel<<<512, 256, 0, stream>>>(emb_i, emb_j, reps, denom, pos, cnt);
  simsum_kernel<<<NT2, 512, 0, stream>>>(reps, denom, pos, cnt, out);
}

// Round 9
// 133.159 us; speedup vs baseline: 2.0960x; 1.0534x over previous
//
#include <hip/hip_runtime.h>
#include <cstdint>
#include <cstddef>

#define NROWS 4096
#define DIM   1024            // elements per row; also BYTES per fp8 row
#define TWON  8192
#define INV_T 2.0f
// exp(2.0) = exp(sim_rr / T) for the masked diagonal (rows are unit-norm)
#define EXP_DIAG 7.38905609893065f
#define NT2   1056            // # of 256x128 tiles covering the upper triangle
#define SCALE1 0x7F7F7F7F     // 4x E8M0 unity scales (127 -> 2^0)

typedef float floatx4 __attribute__((ext_vector_type(4)));
typedef int   intx4   __attribute__((ext_vector_type(4)));
typedef int   intx8   __attribute__((ext_vector_type(8)));

union F8 { intx8 v8; intx4 v4[2]; };

__device__ __forceinline__ void gload16(const uint8_t* g, uint8_t* l) {
  __builtin_amdgcn_global_load_lds(
      (const __attribute__((address_space(1))) void*)g,
      (__attribute__((address_space(3))) void*)l,
      16, 0, 0);
}

// -- kernel 1: normalize -> fp8 reps, fp32 pos dot, zero denom/cnt ------------
// Wave-per-pair, NO barriers, all loads issued up front (full memory-level
// parallelism), HW packed fp8 convert (v_cvt_pk_fp8_f32) instead of the
// __hip_fp8_e4m3 software path. 1024 blocks x 4 waves.
__global__ __launch_bounds__(256) void normpos_kernel(
    const float* __restrict__ emb_i, const float* __restrict__ emb_j,
    uint8_t* __restrict__ reps, float* __restrict__ denom,
    float* __restrict__ pos, unsigned int* __restrict__ cnt) {
  const int t    = threadIdx.x;
  const int lane = t & 63;
  const int wave = t >> 6;
  if (blockIdx.x < 32) denom[blockIdx.x * 256 + t] = 0.f;
  if (blockIdx.x == 32 && t == 0) *cnt = 0u;

  const int k = blockIdx.x * 4 + wave;        // 0..4095 (pair index)
  const float4* pi = reinterpret_cast<const float4*>(emb_i + (size_t)k * DIM);
  const float4* pj = reinterpret_cast<const float4*>(emb_j + (size_t)k * DIM);

  float4 vi[4], vj[4];
#pragma unroll
  for (int q = 0; q < 4; ++q) vi[q] = pi[lane + 64 * q];
#pragma unroll
  for (int q = 0; q < 4; ++q) vj[q] = pj[lane + 64 * q];

  float ssi = 0.f, ssj = 0.f, dot = 0.f;
#pragma unroll
  for (int q = 0; q < 4; ++q) {
    ssi += vi[q].x * vi[q].x + vi[q].y * vi[q].y + vi[q].z * vi[q].z + vi[q].w * vi[q].w;
    ssj += vj[q].x * vj[q].x + vj[q].y * vj[q].y + vj[q].z * vj[q].z + vj[q].w * vj[q].w;
    dot += vi[q].x * vj[q].x + vi[q].y * vj[q].y + vi[q].z * vj[q].z + vi[q].w * vj[q].w;
  }
#pragma unroll
  for (int o = 32; o; o >>= 1) {
    ssi += __shfl_xor(ssi, o, 64);
    ssj += __shfl_xor(ssj, o, 64);
    dot += __shfl_xor(dot, o, 64);
  }
  const float invi = 1.0f / fmaxf(sqrtf(ssi), 1e-12f);
  const float invj = 1.0f / fmaxf(sqrtf(ssj), 1e-12f);

  uint32_t* poi = reinterpret_cast<uint32_t*>(reps + (size_t)k * DIM);
  uint32_t* poj = reinterpret_cast<uint32_t*>(reps + (size_t)(k + NROWS) * DIM);
#pragma unroll
  for (int q = 0; q < 4; ++q) {
    int di = __builtin_amdgcn_cvt_pk_fp8_f32(vi[q].x * invi, vi[q].y * invi, 0, false);
    di     = __builtin_amdgcn_cvt_pk_fp8_f32(vi[q].z * invi, vi[q].w * invi, di, true);
    int dj = __builtin_amdgcn_cvt_pk_fp8_f32(vj[q].x * invj, vj[q].y * invj, 0, false);
    dj     = __builtin_amdgcn_cvt_pk_fp8_f32(vj[q].z * invj, vj[q].w * invj, dj, true);
    poi[lane + 64 * q] = (uint32_t)di;
    poj[lane + 64 * q] = (uint32_t)dj;
  }
  if (lane == 0) pos[k] = dot * invi * invj;   // positive-pair cosine, fp32
}

// ---- kernel 2: fused sim-GEMM (MX-fp8) + exp + row/col sums, upper tri -----
// C-tile 256x128, 512 threads = 8 waves (4x2), each wave 4x4 grid of
// 16x16x128 scaled MFMAs, BK=128 -> 8 staging iters.
// XCD-contiguous remap: blocks are dispatched round-robin over 8 XCDs, so
// tile = (idx&7)*132 + (idx>>3) gives each XCD a CONTIGUOUS triangular range
// -> A-panels stay hot in that XCD's private 4MB L2 (1056 = 8*132 exactly).
// Verified (R6/R7): A-frag A[m=lane&15][k=quad*32+j]; 32B-slot XOR swizzle
// (key=row&3) conflict-free; C/D col=lane&15,row=quad*4+reg.
__global__ __launch_bounds__(512, 4) void simsum_kernel(
    const uint8_t* __restrict__ reps, float* __restrict__ denom,
    const float* __restrict__ pos, unsigned int* __restrict__ cnt,
    float* __restrict__ out) {
  __shared__ __align__(16) uint8_t lA[256 * 128];  // 32 KB
  __shared__ __align__(16) uint8_t lB[128 * 128];  // 16 KB
  __shared__ float dl[256];   // row-side partial sums
  __shared__ float cl[128];   // col-side partial sums
  __shared__ unsigned int is_last;

  const int t    = threadIdx.x;
  const int lane = t & 63;
  const int wave = t >> 6;         // 0..7
  const int wm   = wave >> 1;      // wave row 0..3 (64-row strip)
  const int wn   = wave & 1;       // wave col 0..1 (64-col strip)

  // XCD-contiguous tile id, then unrank: f(bm) = bm*(65-bm) tiles before bm
  const int ridx = ((blockIdx.x & 7) * 132) + (blockIdx.x >> 3);  // 0..1055
  int bm = (int)(32.5f - sqrtf(1056.25f - (float)ridx));
  if (bm < 0) bm = 0;
  if (bm > 31) bm = 31;
  while (bm < 31 && (bm + 1) * (65 - (bm + 1)) <= ridx) ++bm;
  while (bm > 0 && bm * (65 - bm) > ridx) --bm;
  const int bn = 2 * bm + (ridx - bm * (65 - bm));   // 2bm..63

  const uint8_t* gA = reps + (size_t)bm * 256 * DIM;
  const uint8_t* gB = reps + (size_t)bn * 128 * DIM;

  // staging: thread t -> row q*64 + rr (rr=t>>3), 16B half-slot s16=t&7.
  // 32B chunk c32 = (s16>>1)^(rr&3); src byte = c32*32 + (s16&1)*16.
  const int rr  = t >> 3;                                      // 0..63
  const int swz = ((((t >> 1) & 3) ^ (rr & 3)) << 5) | ((t & 1) << 4);

  floatx4 acc[4][4];
#pragma unroll
  for (int i = 0; i < 4; ++i)
#pragma unroll
    for (int j = 0; j < 4; ++j) acc[i][j] = floatx4{0.f, 0.f, 0.f, 0.f};

  const int mrow = lane & 15;        // fragment row select
  const int quad = lane >> 4;        // k block 0..3 (32 bytes each)
  const int soff = (quad ^ (mrow & 3)) << 5;   // 32B slot of this lane's chunk

#pragma unroll 1
  for (int k0 = 0; k0 < DIM; k0 += 128) {
    __syncthreads();
#pragma unroll
    for (int q = 0; q < 4; ++q)   // A: 256 rows
      gload16(gA + (size_t)(q * 64 + rr) * DIM + k0 + swz, lA + q * 8192 + t * 16);
#pragma unroll
    for (int q = 0; q < 2; ++q)   // B: 128 rows
      gload16(gB + (size_t)(q * 64 + rr) * DIM + k0 + swz, lB + q * 8192 + t * 16);
    __syncthreads();   // compiler inserts vmcnt(0) drain here

    F8 fb[4];
#pragma unroll
    for (int nt = 0; nt < 4; ++nt) {
      const uint8_t* p = lB + (wn * 64 + nt * 16 + mrow) * 128 + soff;
      fb[nt].v4[0] = *reinterpret_cast<const intx4*>(p);
      fb[nt].v4[1] = *reinterpret_cast<const intx4*>(p + 16);
    }
#pragma unroll
    for (int mt = 0; mt < 4; ++mt) {
      F8 fa;
      const uint8_t* p = lA + (wm * 64 + mt * 16 + mrow) * 128 + soff;
      fa.v4[0] = *reinterpret_cast<const intx4*>(p);
      fa.v4[1] = *reinterpret_cast<const intx4*>(p + 16);
#pragma unroll
      for (int nt = 0; nt < 4; ++nt)
        acc[mt][nt] = __builtin_amdgcn_mfma_scale_f32_16x16x128_f8f6f4(
            fa.v8, fb[nt].v8, acc[mt][nt], 0, 0, 0, SCALE1, 0, SCALE1);
    }
  }

  if (t < 256) dl[t] = 0.f;
  else if (t < 384) cl[t - 256] = 0.f;
  __syncthreads();

  // half-tile masks (wave-uniform): h = which 128-row half this wave is in
  const int  h       = wm >> 1;
  const int  r128    = 2 * bm + h;
  const bool skipAll = (r128 > bn);    // below-diagonal half (bn==2bm, h==1)
  const bool doCol   = (r128 < bn);    // strictly-above-diagonal half

  // exp in-place: acc now holds e = exp(sim/T)
#pragma unroll
  for (int mt = 0; mt < 4; ++mt)
#pragma unroll
    for (int nt = 0; nt < 4; ++nt)
#pragma unroll
      for (int r = 0; r < 4; ++r)
        acc[mt][nt][r] = __expf(acc[mt][nt][r] * INV_T);

  // row-sums: C/D layout (16x16): col=lane&15, row=quad*4+r
  if (!skipAll) {
#pragma unroll
    for (int mt = 0; mt < 4; ++mt) {
#pragma unroll
      for (int r = 0; r < 4; ++r) {
        float s = acc[mt][0][r] + acc[mt][1][r] + acc[mt][2][r] + acc[mt][3][r];
        s += __shfl_xor(s, 1, 64);
        s += __shfl_xor(s, 2, 64);
        s += __shfl_xor(s, 4, 64);
        s += __shfl_xor(s, 8, 64);
        if ((lane & 15) == 0)
          atomicAdd(&dl[wm * 64 + mt * 16 + quad * 4 + r], s);
      }
    }
  }

  // col-sums (mirror rows), strictly-off-diagonal halves only
  if (doCol) {
#pragma unroll
    for (int nt = 0; nt < 4; ++nt) {
      float c = 0.f;
#pragma unroll
      for (int mt = 0; mt < 4; ++mt)
#pragma unroll
        for (int r = 0; r < 4; ++r) c += acc[mt][nt][r];
      c += __shfl_xor(c, 16, 64);
      c += __shfl_xor(c, 32, 64);
      if (quad == 0)
        atomicAdd(&cl[wn * 64 + nt * 16 + mrow], c);
    }
  }
  __syncthreads();
  if (t < 256) {
    const bool rowOk = !((bn == 2 * bm) && (t >= 128));
    if (rowOk) atomicAdd(&denom[bm * 256 + t], dl[t]);
  } else if (t < 384 && bn > 2 * bm) {
    atomicAdd(&denom[bn * 128 + (t - 256)], cl[t - 256]);
  }
  // __syncthreads drains vmcnt(0): this block's device-scope denom atomics
  // are complete at the coherence point before the counter bump below.
  __syncthreads();
  if (t == 0)
    is_last = (__hip_atomic_fetch_add(cnt, 1u, __ATOMIC_RELAXED,
                                      __HIP_MEMORY_SCOPE_AGENT) == NT2 - 1)
                  ? 1u : 0u;
  __syncthreads();
  if (is_last) {
    float v = 0.f;
#pragma unroll
    for (int i = 0; i < TWON / 512; ++i) {
      float d = __hip_atomic_load(&denom[i * 512 + t], __ATOMIC_RELAXED,
                                  __HIP_MEMORY_SCOPE_AGENT);
      v += __logf(d - EXP_DIAG);
    }
    float p = 0.f;
#pragma unroll
    for (int i = 0; i < NROWS / 512; ++i)
      p += pos[i * 512 + t];
    v -= 4.0f * p;
#pragma unroll
    for (int o = 32; o; o >>= 1) v += __shfl_down(v, o, 64);
    if ((t & 63) == 0) dl[t >> 6] = v;
    __syncthreads();
    if (t == 0) {
      float tot = 0.f;
#pragma unroll
      for (int w = 0; w < 8; ++w) tot += dl[w];
      out[0] = tot * (1.0f / 8192.0f);
    }
  }
}

extern "C" void kernel_launch(void* const* d_in, const int* in_sizes, int n_in,
                              void* d_out, int out_size, void* d_ws, size_t ws_size,
                              hipStream_t stream) {
  const float* emb_i = (const float*)d_in[0];
  const float* emb_j = (const float*)d_in[1];
  float* out = (float*)d_out;

  uint8_t* reps = (uint8_t*)d_ws;                                  // 8.39 MB fp8
  float* denom  = (float*)((char*)d_ws + (size_t)TWON * DIM);      // 32 KB
  float* pos    = denom + TWON;                                    // 16 KB
  unsigned int* cnt = (unsigned int*)(pos + NROWS);

  normpos_kernel<<<1024, 256, 0, stream>>>(emb_i, emb_j, reps, denom, pos, cnt);
  simsum_kernel<<<NT2, 512, 0, stream>>>(reps, denom, pos, cnt, out);
}